// Round 3
// baseline (353.807 us; speedup 1.0000x reference)
//
#include <hip/hip_runtime.h>
#include <hip/hip_bf16.h>

typedef __attribute__((ext_vector_type(8))) short short8_t;
typedef __attribute__((ext_vector_type(4))) short short4_t;
typedef __attribute__((ext_vector_type(4))) float floatx4;
typedef unsigned short ushort_t;
typedef unsigned int uint_t;

#define LDA 36  // A-tile row stride in ushorts: 72 B rows -> near-even bank spread,
                // 8B-aligned fragment reads (ds_read2_b64)

__device__ __forceinline__ uint_t rne_u(float f) {
    // bits 31:16 hold bf16(f), round-to-nearest-even
    uint_t u = __float_as_uint(f);
    return u + (0x7fffu + ((u >> 16) & 1u));
}
// pack bf16(lo) -> [15:0], bf16(hi) -> [31:16]; one v_perm_b32 for the pack
__device__ __forceinline__ uint_t pk2(float lo, float hi) {
    return __builtin_amdgcn_perm(rne_u(hi), rne_u(lo), 0x07060302u);
}
__device__ __forceinline__ floatx4 load4u(const float* p) {
    // 16B load at 4B alignment (kw in {1,2} misaligns); memcpy keeps it legal,
    // backend emits global_load_dwordx4 (unaligned-access-mode on gfx950)
    floatx4 r;
    __builtin_memcpy(&r, p, 16);
    return r;
}

// one-time transpose/convert: w2[co][khw*64+ci] = bf16(w[co][ci*9+khw])
__global__ void w2_prepass(const float* __restrict__ w, ushort_t* __restrict__ w2) {
    int idx = blockIdx.x * 256 + threadIdx.x;  // exactly 73728
    int co  = idx / 576;
    int k   = idx - co * 576;
    int khw = k >> 6, ci = k & 63;
    w2[idx] = (ushort_t)(rne_u(w[co * 576 + ci * 9 + khw]) >> 16);
}

// Block = one output row: m = wo in [0,128) (126 valid + 2 pad), all 128 c_out.
// K-order (kh,kw,ci): 18 iters of K=32 (fixed kh,kw + 32 ci) -> A staging is
// m-contiguous vector loads; B fragments come straight from global w2 (bf16).
__global__ void conv_min_tanh_kernel(const float* __restrict__ x,
                                     const float* __restrict__ w,
                                     const ushort_t* __restrict__ w2,
                                     const float* __restrict__ bias,
                                     float* __restrict__ out,
                                     int use_w2)
{
    __shared__ ushort_t Atile[128 * LDA];
    __shared__ float red[2][128];

    const int tid = threadIdx.x;
    const int bid = blockIdx.x;
    const int n   = bid / 126;
    const int ho  = bid - n * 126;

    const int tx = tid & 31;   // m-group: 4 consecutive m
    const int ty = tid >> 5;   // ci-group: 4 consecutive ci (of the 32 in this K-block)

    const float* xrow = x + ((size_t)n << 20) + (size_t)ho * 128;  // &x[n][0][ho][0]
    const bool risky = (bid == 4031);  // only block whose kh=2,kw=2,ci=63 tail reads past x

    const int lane = tid & 63;
    const int wid  = tid >> 6;
    const int wm   = wid >> 1;  // m-half of 128x128 tile
    const int wn   = wid & 1;   // co-half
    const int r16  = lane & 15;
    const int quad = lane >> 4;

    floatx4 acc[4][4];
#pragma unroll
    for (int i = 0; i < 4; ++i)
#pragma unroll
        for (int j = 0; j < 4; ++j)
            acc[i][j] = (floatx4){0.f, 0.f, 0.f, 0.f};

    // per-lane base into w2 for B fragments: row co = wn*64 + t4*16 + r16, k = khw*64+ci0+quad*8
    const ushort_t* w2base = w2 + (size_t)(wn * 64 + r16) * 576 + quad * 8;
    const float*    wbase  = w + (size_t)(wn * 64 + r16) * 576;  // fallback path

    for (int it = 0; it < 18; ++it) {
        const int khw = it >> 1;
        const int ci0 = (it & 1) << 5;
        const int kh  = khw / 3;
        const int kw  = khw - kh * 3;

        // ---- B fragments: direct global loads (16B aligned, L1/L2 hits) ----
        short8_t bfr[4];
        if (use_w2) {
            const ushort_t* bb = w2base + khw * 64 + ci0;
#pragma unroll
            for (int t4 = 0; t4 < 4; ++t4)
                bfr[t4] = *reinterpret_cast<const short8_t*>(bb + (size_t)t4 * (16 * 576));
        } else {
            // rare fallback (ws too small): strided gather + convert from f32 w
#pragma unroll
            for (int t4 = 0; t4 < 4; ++t4) {
                const float* wp = wbase + (size_t)t4 * (16 * 576) + (size_t)(ci0 + quad * 8) * 9 + khw;
                short8_t b;
#pragma unroll
                for (int q = 0; q < 4; ++q) {
                    uint_t u = pk2(wp[(2 * q) * 9], wp[(2 * q + 1) * 9]);
                    b[2 * q]     = (short)(u & 0xffffu);
                    b[2 * q + 1] = (short)(u >> 16);
                }
                bfr[t4] = b;
            }
        }

        // ---- A global loads: 4 x dwordx4, m-contiguous ----
        floatx4 dv[4];
        if (!risky) {
            const float* ab = xrow + kh * 128 + kw + tx * 4;
#pragma unroll
            for (int j = 0; j < 4; ++j)
                dv[j] = load4u(ab + (size_t)(ci0 + ty * 4 + j) * 16384);
        } else {
            const long long lim = 33554431;  // last valid x element
#pragma unroll
            for (int j = 0; j < 4; ++j)
#pragma unroll
                for (int i = 0; i < 4; ++i) {
                    long long g = ((long long)n << 20) + (long long)(ci0 + ty * 4 + j) * 16384
                                + (long long)(ho + kh) * 128 + kw + tx * 4 + i;
                    if (g > lim) g = lim;  // clamped lanes feed only pad rows m=126,127
                    dv[j][i] = x[g];
                }
        }

        __syncthreads();  // previous iter's fragment reads complete

        // ---- convert + transpose-write A tile: per m, 4 ci bf16 (one b64) ----
#pragma unroll
        for (int i = 0; i < 4; ++i) {
            uint2 u;
            u.x = pk2(dv[0][i], dv[1][i]);
            u.y = pk2(dv[2][i], dv[3][i]);
            *reinterpret_cast<uint2*>(&Atile[(tx * 4 + i) * LDA + ty * 4]) = u;
        }
        __syncthreads();  // tile visible

        // ---- A fragments from LDS (two b64 reads, 8B aligned) + MFMA ----
        short8_t afr[4];
#pragma unroll
        for (int t4 = 0; t4 < 4; ++t4) {
            const ushort_t* ap = &Atile[(wm * 64 + t4 * 16 + r16) * LDA + quad * 8];
            short4_t lo = *reinterpret_cast<const short4_t*>(ap);
            short4_t hi = *reinterpret_cast<const short4_t*>(ap + 4);
            afr[t4] = __builtin_shufflevector(lo, hi, 0, 1, 2, 3, 4, 5, 6, 7);
        }
#pragma unroll
        for (int tm = 0; tm < 4; ++tm)
#pragma unroll
            for (int tn = 0; tn < 4; ++tn)
                acc[tm][tn] = __builtin_amdgcn_mfma_f32_16x16x32_bf16(
                    afr[tm], bfr[tn], acc[tm][tn], 0, 0, 0);
    }

    // ---- epilogue: +bias, min over co, cross-lane/cross-wave min, tanh(tanh) ----
    float bvv[4];
#pragma unroll
    for (int tn = 0; tn < 4; ++tn)
        bvv[tn] = bias[wn * 64 + tn * 16 + r16];

#pragma unroll
    for (int tm = 0; tm < 4; ++tm) {
#pragma unroll
        for (int r = 0; r < 4; ++r) {
            // C/D layout: row(m) = quad*4 + r, col(co) = r16
            float v = acc[tm][0][r] + bvv[0];
            v = fminf(v, acc[tm][1][r] + bvv[1]);
            v = fminf(v, acc[tm][2][r] + bvv[2]);
            v = fminf(v, acc[tm][3][r] + bvv[3]);
            v = fminf(v, __shfl_xor(v, 1, 64));
            v = fminf(v, __shfl_xor(v, 2, 64));
            v = fminf(v, __shfl_xor(v, 4, 64));
            v = fminf(v, __shfl_xor(v, 8, 64));
            if (r16 == 0)
                red[wn][wm * 64 + tm * 16 + quad * 4 + r] = v;
        }
    }
    __syncthreads();

    if (tid < 126) {  // m=126,127 are padding
        float v = fminf(red[0][tid], red[1][tid]);
        v = tanhf(tanhf(v));
        out[bid * 126 + tid] = v;  // out flat [n][ho][wo]
    }
}

extern "C" void kernel_launch(void* const* d_in, const int* in_sizes, int n_in,
                              void* d_out, int out_size, void* d_ws, size_t ws_size,
                              hipStream_t stream) {
    const float* x    = (const float*)d_in[0];   // [32,64,128,128] f32
    const float* w    = (const float*)d_in[1];   // [128,64,3,3] f32
    const float* bias = (const float*)d_in[2];   // [128] f32
    float* out = (float*)d_out;                  // [32,1,126,126] f32

    const int use_w2 = (ws_size >= (size_t)(73728 * 2)) ? 1 : 0;
    ushort_t* w2 = (ushort_t*)d_ws;

    if (use_w2)
        w2_prepass<<<dim3(288), dim3(256), 0, stream>>>(w, w2);

    // 32 images x 126 output rows = 4032 blocks, one row (126+2 pad pixels) each
    conv_min_tanh_kernel<<<dim3(4032), dim3(256), 0, stream>>>(x, w, w2, bias, out, use_w2);
}

// Round 4
// 347.233 us; speedup vs baseline: 1.0189x; 1.0189x over previous
//
#include <hip/hip_runtime.h>
#include <hip/hip_bf16.h>

typedef __attribute__((ext_vector_type(8))) short short8_t;
typedef __attribute__((ext_vector_type(4))) float floatx4;
typedef __attribute__((ext_vector_type(4))) unsigned int uint4_t;
typedef unsigned short ushort_t;
typedef unsigned int uint_t;

#define ROWS 132   // tile rows = x columns 0..129 read (+2 spare); 128..131 zeroed once
#define RSTR 72    // ushorts per row = 9 chunks16; odd chunk count -> even bank spread

__device__ __forceinline__ uint_t rne_u(float f) {
    uint_t u = __float_as_uint(f);
    return u + (0x7fffu + ((u >> 16) & 1u));   // bf16(f) in bits[31:16], RNE
}
__device__ __forceinline__ uint_t pk2(float lo, float hi) {
    // bf16(lo)->[15:0], bf16(hi)->[31:16]; one v_perm_b32
    return __builtin_amdgcn_perm(rne_u(hi), rne_u(lo), 0x07060302u);
}

// one-time transpose/convert: w2[co][khw*64+ci] = bf16(w[co][ci*9+khw])
__global__ void w2_prepass(const float* __restrict__ w, ushort_t* __restrict__ w2) {
    int idx = blockIdx.x * 256 + threadIdx.x;  // exactly 73728
    int co  = idx / 576;
    int k   = idx - co * 576;
    int khw = k >> 6, ci = k & 63;
    w2[idx] = (ushort_t)(rne_u(w[co * 576 + ci * 9 + khw]) >> 16);
}

// Block = one output row (128 m = wo, 126 valid + 2 pad) x all 128 c_out.
// 3 kh-stages: stage loads x row ho+kh (all 64 ci, cols 0..127, aligned dwordx4),
// transposes to LDS tile T[col][ci] bf16 (xor-swizzled 16B chunks), then runs
// 6 MFMA rounds (kw 0..2 x ci-half 0..1) reading A frags at row col=wo+kw.
// Stage kh+1's global loads issue before stage kh's MFMA phase (prefetch).
__global__ __launch_bounds__(256, 2)
void conv_min_tanh_kernel(const float* __restrict__ x,
                          const float* __restrict__ w,
                          const ushort_t* __restrict__ w2,
                          const float* __restrict__ bias,
                          float* __restrict__ out,
                          int use_w2)
{
    __shared__ ushort_t T[ROWS * RSTR];   // 19,008 B
    __shared__ float red[2][128];

    const int tid = threadIdx.x;
    const int bid = blockIdx.x;
    const int n   = bid / 126;
    const int ho  = bid - n * 126;

    const int tx = tid & 31;   // column chunk: cols 4tx..4tx+3
    const int ty = tid >> 5;   // ci chunk: ci = 8ty..8ty+7

    const int lane = tid & 63;
    const int wid  = tid >> 6;
    const int wm   = wid >> 1;  // m-half of 128x128 tile
    const int wn   = wid & 1;   // co-half
    const int r16  = lane & 15;
    const int quad = lane >> 4;

    // zero pad rows 128..131 (read as A rows for pad outputs m=126,127)
    if (tid < 144)
        reinterpret_cast<uint_t*>(T)[(128 * RSTR) / 2 + tid] = 0u;

    const float* xbase = x + ((size_t)n << 20) + (size_t)ho * 128;  // + ci*16384 + kh*128 + col

    // prologue: stage kh=0 global loads (8 x dwordx4, 16B aligned)
    floatx4 dv[8];
#pragma unroll
    for (int j = 0; j < 8; ++j)
        dv[j] = *reinterpret_cast<const floatx4*>(xbase + (size_t)(ty * 8 + j) * 16384 + tx * 4);

    floatx4 acc[4][4];
#pragma unroll
    for (int i = 0; i < 4; ++i)
#pragma unroll
        for (int j = 0; j < 4; ++j)
            acc[i][j] = (floatx4){0.f, 0.f, 0.f, 0.f};

    const ushort_t* w2base = w2 + (size_t)(wn * 64 + r16) * 576 + quad * 8;
    const float*    wbase  = w + (size_t)(wn * 64 + r16) * 576;  // fallback

    for (int kh = 0; kh < 3; ++kh) {
        __syncthreads();  // all reads of previous stage's tile complete

        // convert + transpose-write: per col c=4tx+i, one b128 = ci 8ty..8ty+7
#pragma unroll
        for (int i = 0; i < 4; ++i) {
            uint4_t u;
            u.x = pk2(dv[0][i], dv[1][i]);
            u.y = pk2(dv[2][i], dv[3][i]);
            u.z = pk2(dv[4][i], dv[5][i]);
            u.w = pk2(dv[6][i], dv[7][i]);
            const int c   = tx * 4 + i;
            const int p16 = ty ^ ((c >> 3) & 7);  // xor-swizzled chunk16 slot
            *reinterpret_cast<uint4_t*>(&T[c * RSTR + p16 * 8]) = u;
        }

        // prefetch next stage's x row (consumed after next barrier pair)
        if (kh < 2) {
#pragma unroll
            for (int j = 0; j < 8; ++j)
                dv[j] = *reinterpret_cast<const floatx4*>(
                    xbase + (size_t)(ty * 8 + j) * 16384 + (kh + 1) * 128 + tx * 4);
        }

        __syncthreads();  // tile ready

        // 6 MFMA rounds: kw 0..2 x ci-half 0..1, K=32 each
#pragma unroll
        for (int kw = 0; kw < 3; ++kw) {
#pragma unroll
            for (int half = 0; half < 2; ++half) {
                const int khw = kh * 3 + kw;

                short8_t bfr[4];
                if (use_w2) {
                    const ushort_t* bb = w2base + khw * 64 + half * 32;
#pragma unroll
                    for (int t4 = 0; t4 < 4; ++t4)
                        bfr[t4] = *reinterpret_cast<const short8_t*>(bb + (size_t)t4 * (16 * 576));
                } else {
#pragma unroll
                    for (int t4 = 0; t4 < 4; ++t4) {
                        const float* wp = wbase + (size_t)t4 * (16 * 576)
                                        + (size_t)(half * 32 + quad * 8) * 9 + khw;
                        short8_t b;
#pragma unroll
                        for (int q = 0; q < 4; ++q) {
                            uint_t u = pk2(wp[(2 * q) * 9], wp[(2 * q + 1) * 9]);
                            b[2 * q]     = (short)(u & 0xffffu);
                            b[2 * q + 1] = (short)(u >> 16);
                        }
                        bfr[t4] = b;
                    }
                }

                short8_t afr[4];
#pragma unroll
                for (int t4 = 0; t4 < 4; ++t4) {
                    const int c   = wm * 64 + t4 * 16 + r16 + kw;       // tile row (x col)
                    const int p16 = (half * 4 + quad) ^ ((c >> 3) & 7); // matching swizzle
                    afr[t4] = *reinterpret_cast<const short8_t*>(&T[c * RSTR + p16 * 8]);
                }
#pragma unroll
                for (int tm = 0; tm < 4; ++tm)
#pragma unroll
                    for (int tn = 0; tn < 4; ++tn)
                        acc[tm][tn] = __builtin_amdgcn_mfma_f32_16x16x32_bf16(
                            afr[tm], bfr[tn], acc[tm][tn], 0, 0, 0);
            }
        }
    }

    // epilogue: +bias, min over co, cross-lane/cross-wave min, tanh(tanh)
    float bvv[4];
#pragma unroll
    for (int tn = 0; tn < 4; ++tn)
        bvv[tn] = bias[wn * 64 + tn * 16 + r16];

#pragma unroll
    for (int tm = 0; tm < 4; ++tm) {
#pragma unroll
        for (int r = 0; r < 4; ++r) {
            // C/D layout: row(m) = quad*4 + r, col(co) = r16
            float v = acc[tm][0][r] + bvv[0];
            v = fminf(v, acc[tm][1][r] + bvv[1]);
            v = fminf(v, acc[tm][2][r] + bvv[2]);
            v = fminf(v, acc[tm][3][r] + bvv[3]);
            v = fminf(v, __shfl_xor(v, 1, 64));
            v = fminf(v, __shfl_xor(v, 2, 64));
            v = fminf(v, __shfl_xor(v, 4, 64));
            v = fminf(v, __shfl_xor(v, 8, 64));
            if (r16 == 0)
                red[wn][wm * 64 + tm * 16 + quad * 4 + r] = v;
        }
    }
    __syncthreads();

    if (tid < 126) {  // m=126,127 are padding
        float v = fminf(red[0][tid], red[1][tid]);
        v = tanhf(tanhf(v));
        out[bid * 126 + tid] = v;  // out flat [n][ho][wo]
    }
}

extern "C" void kernel_launch(void* const* d_in, const int* in_sizes, int n_in,
                              void* d_out, int out_size, void* d_ws, size_t ws_size,
                              hipStream_t stream) {
    const float* x    = (const float*)d_in[0];   // [32,64,128,128] f32
    const float* w    = (const float*)d_in[1];   // [128,64,3,3] f32
    const float* bias = (const float*)d_in[2];   // [128] f32
    float* out = (float*)d_out;                  // [32,1,126,126] f32

    const int use_w2 = (ws_size >= (size_t)(73728 * 2)) ? 1 : 0;
    ushort_t* w2 = (ushort_t*)d_ws;

    if (use_w2)
        w2_prepass<<<dim3(288), dim3(256), 0, stream>>>(w, w2);

    // 32 images x 126 output rows = 4032 blocks, one row each
    conv_min_tanh_kernel<<<dim3(4032), dim3(256), 0, stream>>>(x, w, w2, bias, out, use_w2);
}

// Round 5
// 338.905 us; speedup vs baseline: 1.0440x; 1.0246x over previous
//
#include <hip/hip_runtime.h>
#include <hip/hip_bf16.h>

typedef __attribute__((ext_vector_type(8))) short short8_t;
typedef __attribute__((ext_vector_type(4))) float floatx4;
typedef unsigned short ushort_t;
typedef unsigned int uint_t;

#define RSTR 72        // shorts per tile column (9 x 16B chunks; odd -> spread banks)
#define TSZ  (132 * RSTR)  // shorts per x-row tile (cols 0..131)

__device__ __forceinline__ uint_t rne_u(float f) {
    uint_t u = __float_as_uint(f);
    return u + (0x7fffu + ((u >> 16) & 1u));   // bf16(f) in bits[31:16], RNE
}
__device__ __forceinline__ uint_t pk2(float lo, float hi) {
    return __builtin_amdgcn_perm(rne_u(hi), rne_u(lo), 0x07060302u);
}

// one-time transpose/convert: w2[co][khw*64+ci] = bf16(w[co][ci*9+khw])
__global__ void w2_prepass(const float* __restrict__ w, ushort_t* __restrict__ w2) {
    int idx = blockIdx.x * 256 + threadIdx.x;  // exactly 73728
    int co  = idx / 576;
    int k   = idx - co * 576;
    int khw = k >> 6, ci = k & 63;
    w2[idx] = (ushort_t)(rne_u(w[co * 576 + ci * 9 + khw]) >> 16);
}

// Block = 2 output rows (ho0, ho0+1) x 128 wo x 128 co. 512 threads = 8 waves.
// Stages: 4 x-rows (ho0..ho0+3) loaded up-front (4 dwordx4/thread), converted to
// 4 LDS tiles T[s][col][ci] bf16 (xor chunk swizzle), ONE barrier, then 18 MFMA
// rounds (kh,kw,ci-half) straight through. A frags: tile s=(m>>7)+kh, col wo+kw.
// B frags: global w2 with one-round register prefetch.
__global__ __launch_bounds__(512, 4)
void conv_min_tanh_kernel(const float* __restrict__ x,
                          const float* __restrict__ w,
                          const ushort_t* __restrict__ w2,
                          const float* __restrict__ bias,
                          float* __restrict__ out,
                          int use_w2)
{
    __shared__ ushort_t T[4 * TSZ];    // 76,032 B
    __shared__ float red[2][256];      // 2,048 B

    const int tid  = threadIdx.x;
    const int bid  = blockIdx.x;
    const int n    = bid / 63;
    const int ho0  = (bid - n * 63) * 2;

    const int tx = tid & 31;   // cols 4tx..4tx+3
    const int ty = tid >> 5;   // ci 4ty..4ty+3 (0..15)

    const int lane = tid & 63;
    const int wid  = tid >> 6;         // 0..7
    const int wm   = wid >> 1;         // m-quarter (64 rows each; wm>>1 = out-row)
    const int wn   = wid & 1;          // co-half
    const int r16  = lane & 15;
    const int quad = lane >> 4;

    const float* xbase = x + ((size_t)n << 20) + (size_t)ho0 * 128;

    // ---- issue ALL 4 x-row loads up-front (16 x dwordx4 in flight) ----
    floatx4 dv[4][4];
#pragma unroll
    for (int s = 0; s < 4; ++s)
#pragma unroll
        for (int j = 0; j < 4; ++j)
            dv[s][j] = *reinterpret_cast<const floatx4*>(
                xbase + (size_t)(ty * 4 + j) * 16384 + s * 128 + tx * 4);

    // zero pad cols 128..131 of each tile (feed pad outputs wo=126,127)
    for (int idx = tid; idx < 576; idx += 512) {
        int s = idx / 144, o = idx - s * 144;
        reinterpret_cast<uint_t*>(T)[s * (TSZ / 2) + (128 * RSTR) / 2 + o] = 0u;
    }

    // ---- convert + transpose-write tiles as loads land ----
#pragma unroll
    for (int s = 0; s < 4; ++s) {
#pragma unroll
        for (int i = 0; i < 4; ++i) {
            uint2 u;
            u.x = pk2(dv[s][0][i], dv[s][1][i]);   // ci 4ty, 4ty+1
            u.y = pk2(dv[s][2][i], dv[s][3][i]);   // ci 4ty+2, 4ty+3
            const int c   = tx * 4 + i;
            const int swz = (ty >> 1) ^ ((c >> 3) & 7);   // 16B-chunk xor swizzle
            *reinterpret_cast<uint2*>(&T[s * TSZ + c * RSTR + swz * 8 + (ty & 1) * 4]) = u;
        }
    }

    floatx4 acc[4][4];
#pragma unroll
    for (int i = 0; i < 4; ++i)
#pragma unroll
        for (int j = 0; j < 4; ++j)
            acc[i][j] = (floatx4){0.f, 0.f, 0.f, 0.f};

    const ushort_t* w2base = w2 + (size_t)(wn * 64 + r16) * 576 + quad * 8;
    const float*    wbase  = w + (size_t)(wn * 64 + r16) * 576;  // fallback

    __syncthreads();  // all tiles ready; the only staging barrier

    // ---- 18 rounds: kh(0..2) x kw(0..2) x ci-half(0..1), K=32 each ----
    short8_t bcur[4], bnxt[4];
    // preload round 0's B
    if (use_w2) {
#pragma unroll
        for (int t4 = 0; t4 < 4; ++t4)
            bcur[t4] = *reinterpret_cast<const short8_t*>(w2base + (size_t)t4 * (16 * 576));
    } else {
#pragma unroll
        for (int t4 = 0; t4 < 4; ++t4) {
            const float* wp = wbase + (size_t)t4 * (16 * 576) + (size_t)(quad * 8) * 9;
            short8_t b;
#pragma unroll
            for (int q = 0; q < 4; ++q) {
                uint_t u = pk2(wp[(2 * q) * 9], wp[(2 * q + 1) * 9]);
                b[2 * q]     = (short)(u & 0xffffu);
                b[2 * q + 1] = (short)(u >> 16);
            }
            bcur[t4] = b;
        }
    }

#pragma unroll
    for (int rd = 0; rd < 18; ++rd) {
        const int khw  = rd >> 1;           // kh*3+kw
        const int kh   = khw / 3;
        const int kw   = khw - kh * 3;
        const int half = rd & 1;

        // prefetch next round's B fragments
        if (rd < 17) {
            const int khw2 = (rd + 1) >> 1, half2 = (rd + 1) & 1;
            if (use_w2) {
                const ushort_t* bb = w2base + khw2 * 64 + half2 * 32;
#pragma unroll
                for (int t4 = 0; t4 < 4; ++t4)
                    bnxt[t4] = *reinterpret_cast<const short8_t*>(bb + (size_t)t4 * (16 * 576));
            } else {
#pragma unroll
                for (int t4 = 0; t4 < 4; ++t4) {
                    const float* wp = wbase + (size_t)t4 * (16 * 576)
                                    + (size_t)(half2 * 32 + quad * 8) * 9 + khw2;
                    short8_t b;
#pragma unroll
                    for (int q = 0; q < 4; ++q) {
                        uint_t u = pk2(wp[(2 * q) * 9], wp[(2 * q + 1) * 9]);
                        b[2 * q]     = (short)(u & 0xffffu);
                        b[2 * q + 1] = (short)(u >> 16);
                    }
                    bnxt[t4] = b;
                }
            }
        }

        // A fragments from LDS: m = wm*64 + t4*16 + r16 -> out-row m>>7, wo m&127
        short8_t afr[4];
#pragma unroll
        for (int t4 = 0; t4 < 4; ++t4) {
            const int m  = wm * 64 + t4 * 16 + r16;
            const int s  = (m >> 7) + kh;
            const int c  = (m & 127) + kw;
            const int sw = (half * 4 + quad) ^ ((c >> 3) & 7);
            afr[t4] = *reinterpret_cast<const short8_t*>(&T[s * TSZ + c * RSTR + sw * 8]);
        }
#pragma unroll
        for (int tm = 0; tm < 4; ++tm)
#pragma unroll
            for (int tn = 0; tn < 4; ++tn)
                acc[tm][tn] = __builtin_amdgcn_mfma_f32_16x16x32_bf16(
                    afr[tm], bcur[tn], acc[tm][tn], 0, 0, 0);

#pragma unroll
        for (int t4 = 0; t4 < 4; ++t4)
            bcur[t4] = bnxt[t4];
    }

    // ---- epilogue: +bias, min over co, cross-lane/wave min, tanh(tanh) ----
    float bvv[4];
#pragma unroll
    for (int tn = 0; tn < 4; ++tn)
        bvv[tn] = bias[wn * 64 + tn * 16 + r16];

#pragma unroll
    for (int tm = 0; tm < 4; ++tm) {
#pragma unroll
        for (int r = 0; r < 4; ++r) {
            // C/D: row(m) = quad*4 + r, col(co) = r16
            float v = acc[tm][0][r] + bvv[0];
            v = fminf(v, acc[tm][1][r] + bvv[1]);
            v = fminf(v, acc[tm][2][r] + bvv[2]);
            v = fminf(v, acc[tm][3][r] + bvv[3]);
            v = fminf(v, __shfl_xor(v, 1, 64));
            v = fminf(v, __shfl_xor(v, 2, 64));
            v = fminf(v, __shfl_xor(v, 4, 64));
            v = fminf(v, __shfl_xor(v, 8, 64));
            if (r16 == 0)
                red[wn][wm * 64 + tm * 16 + quad * 4 + r] = v;
        }
    }
    __syncthreads();

    if (tid < 256) {
        const int r  = tid >> 7;       // out-row within pair
        const int wo = tid & 127;
        if (wo < 126) {
            float v = fminf(red[0][tid], red[1][tid]);
            v = tanhf(tanhf(v));
            out[((size_t)n * 126 + ho0 + r) * 126 + wo] = v;
        }
    }
}

extern "C" void kernel_launch(void* const* d_in, const int* in_sizes, int n_in,
                              void* d_out, int out_size, void* d_ws, size_t ws_size,
                              hipStream_t stream) {
    const float* x    = (const float*)d_in[0];   // [32,64,128,128] f32
    const float* w    = (const float*)d_in[1];   // [128,64,3,3] f32
    const float* bias = (const float*)d_in[2];   // [128] f32
    float* out = (float*)d_out;                  // [32,1,126,126] f32

    const int use_w2 = (ws_size >= (size_t)(73728 * 2)) ? 1 : 0;
    ushort_t* w2 = (ushort_t*)d_ws;

    if (use_w2)
        w2_prepass<<<dim3(288), dim3(256), 0, stream>>>(w, w2);

    // 32 images x 63 row-pairs = 2016 blocks
    conv_min_tanh_kernel<<<dim3(2016), dim3(512), 0, stream>>>(x, w, w2, bias, out, use_w2);
}